// Round 15
// baseline (6001.286 us; speedup 1.0000x reference)
//
#include <hip/hip_runtime.h>
#include <hip/hip_fp16.h>
#include <math.h>
#include <utility>

#define NN    6000
#define NPAD  6144
#define NIB   1200
#define NMAXI 80
#define NAVGI 30
#define NBLK  250
#define NTHR  512   // 8 waves/block, 3 rows per wave -> 24 rows/block

#define SQRT_PI_F 1.7724538509055160273f

typedef _Float16 half2_t __attribute__((ext_vector_type(2)));

// ---- physical-AGPR pin via textual register tokens (round-14 fix: the
// "n" operand printed immediates >64 as hex, producing invalid "a0x41").
#define A_EACH(X) \
  X(0) X(1) X(2) X(3) X(4) X(5) X(6) X(7) \
  X(8) X(9) X(10) X(11) X(12) X(13) X(14) X(15) \
  X(16) X(17) X(18) X(19) X(20) X(21) X(22) X(23) \
  X(24) X(25) X(26) X(27) X(28) X(29) X(30) X(31) \
  X(32) X(33) X(34) X(35) X(36) X(37) X(38) X(39) \
  X(40) X(41) X(42) X(43) X(44) X(45) X(46) X(47) \
  X(48) X(49) X(50) X(51) X(52) X(53) X(54) X(55) \
  X(56) X(57) X(58) X(59) X(60) X(61) X(62) X(63) \
  X(64) X(65) X(66) X(67) X(68) X(69) X(70) X(71) \
  X(72) X(73) X(74) X(75) X(76) X(77) X(78) X(79) \
  X(80) X(81) X(82) X(83) X(84) X(85) X(86) X(87) \
  X(88) X(89) X(90) X(91) X(92) X(93) X(94) X(95) \
  X(96) X(97) X(98) X(99) X(100) X(101) X(102) X(103) \
  X(104) X(105) X(106) X(107) X(108) X(109) X(110) X(111) \
  X(112) X(113) X(114) X(115) X(116) X(117) X(118) X(119) \
  X(120) X(121) X(122) X(123) X(124) X(125) X(126) X(127) \
  X(128) X(129) X(130) X(131) X(132) X(133) X(134) X(135) \
  X(136) X(137) X(138) X(139) X(140) X(141) X(142) X(143)

template <int N> struct Agpr;
#define DEFA(NUM)                                                             \
  template <> struct Agpr<NUM> {                                              \
    static __device__ __forceinline__ void w(unsigned v) {                    \
      asm volatile("v_accvgpr_write_b32 a" #NUM ", %0" :: "v"(v));            \
    }                                                                         \
    static __device__ __forceinline__ unsigned r() {                          \
      unsigned x;                                                             \
      asm volatile("v_accvgpr_read_b32 %0, a" #NUM : "=v"(x));                \
      return x;                                                               \
    }                                                                         \
  };
A_EACH(DEFA)
#undef DEFA

template <int N> __device__ __forceinline__ void aw(unsigned v) { Agpr<N>::w(v); }
template <int N> __device__ __forceinline__ unsigned ar() { return Agpr<N>::r(); }

// Entry clobber: forces .agpr_count >= 144 so HW allocates a0..a143.
__device__ __forceinline__ void reserve_agprs() {
  asm volatile("" :::
    "a0","a1","a2","a3","a4","a5","a6","a7","a8","a9","a10","a11","a12","a13",
    "a14","a15","a16","a17","a18","a19","a20","a21","a22","a23","a24","a25",
    "a26","a27","a28","a29","a30","a31","a32","a33","a34","a35","a36","a37",
    "a38","a39","a40","a41","a42","a43","a44","a45","a46","a47","a48","a49",
    "a50","a51","a52","a53","a54","a55","a56","a57","a58","a59","a60","a61",
    "a62","a63","a64","a65","a66","a67","a68","a69","a70","a71","a72","a73",
    "a74","a75","a76","a77","a78","a79","a80","a81","a82","a83","a84","a85",
    "a86","a87","a88","a89","a90","a91","a92","a93","a94","a95","a96","a97",
    "a98","a99","a100","a101","a102","a103","a104","a105","a106","a107",
    "a108","a109","a110","a111","a112","a113","a114","a115","a116","a117",
    "a118","a119","a120","a121","a122","a123","a124","a125","a126","a127",
    "a128","a129","a130","a131","a132","a133","a134","a135","a136","a137",
    "a138","a139","a140","a141","a142","a143");
}

// Inline erfcx, no libcalls (NR erfcc transform; exp(x^2) cancels analytically)
__device__ __forceinline__ float erfcx_inl(float y) {
  y = fminf(fmaxf(y, -9.0f), 25.0f);
  const float a   = fabsf(y);
  const float a_s = fminf(a, 5.0f);
  const float t   = 1.0f / (1.0f + 0.5f * a_s);
  const float p   = -1.26551223f + t * (1.00002368f + t * (0.37409196f +
                    t * (0.09678418f + t * (-0.18628806f + t * (0.27886807f +
                    t * (-1.13520398f + t * (1.48851587f + t * (-0.82215223f +
                    t * 0.17087277f))))))));
  const float fsm = t * __expf(p);
  const float a_l = fmaxf(a, 5.0f);
  const float flg = (1.0f / (SQRT_PI_F * a_l)) * (1.0f - 0.5f / (a_l * a_l));
  const float f   = (a <= 5.0f) ? fsm : flg;
  return (y >= 0.0f) ? f : 2.0f * __expf(y * y) - f;
}

__device__ __forceinline__ float dot2acc(unsigned w, unsigned r, float acc) {
#if defined(__has_builtin) && __has_builtin(__builtin_amdgcn_fdot2)
  return __builtin_amdgcn_fdot2(__builtin_bit_cast(half2_t, w),
                                __builtin_bit_cast(half2_t, r), acc, false);
#else
  half2_t wh = __builtin_bit_cast(half2_t, w);
  half2_t rh = __builtin_bit_cast(half2_t, r);
  return acc + (float)wh.x * (float)rh.x + (float)wh.y * (float)rh.y;
#endif
}

__device__ __forceinline__ unsigned pksq(unsigned w) {
  half2_t wh = __builtin_bit_cast(half2_t, w);
  half2_t s  = wh * wh;
  return __builtin_bit_cast(unsigned, s);
}

// Inline sense-reversing global barrier (proven rounds 6-13, 250 blocks).
__device__ __forceinline__ void gbar(unsigned* cnt, unsigned* gen, int tid) {
  __syncthreads();
  if (tid == 0) {
    __builtin_amdgcn_fence(__ATOMIC_RELEASE, "agent");
    const unsigned g = __hip_atomic_load(gen, __ATOMIC_RELAXED,
                                         __HIP_MEMORY_SCOPE_AGENT);
    const unsigned old = __hip_atomic_fetch_add(cnt, 1u, __ATOMIC_RELAXED,
                                                __HIP_MEMORY_SCOPE_AGENT);
    if (old == NBLK - 1) {
      __hip_atomic_store(cnt, 0u, __ATOMIC_RELAXED, __HIP_MEMORY_SCOPE_AGENT);
      __hip_atomic_store(gen, g + 1u, __ATOMIC_RELEASE,
                         __HIP_MEMORY_SCOPE_AGENT);
    } else {
      while (__hip_atomic_load(gen, __ATOMIC_RELAXED,
                               __HIP_MEMORY_SCOPE_AGENT) == g)
        __builtin_amdgcn_s_sleep(2);
    }
    __builtin_amdgcn_fence(__ATOMIC_ACQUIRE, "agent");
  }
  __syncthreads();
}

__global__ __launch_bounds__(256) void init_kernel(
    const float* __restrict__ contrast, const float* __restrict__ grat,
    const float* __restrict__ pref, float* __restrict__ g0,
    float* __restrict__ g1, float* __restrict__ meanv,
    float* __restrict__ ctab, float* __restrict__ qn, float* __restrict__ qw,
    unsigned* __restrict__ conv, unsigned* __restrict__ bar)
{
  int t = blockIdx.x * 256 + threadIdx.x;
  if (t < NPAD) { g0[t] = 0.0f; g1[t] = 0.0f; }
  if (t < NN) {
    double th = (3.141592653589793 - 0.01) * (double)t / 5999.0;
    ctab[t] = cosf(2.0f * (float)th) - 1.0f;
    float d  = grat[0] - pref[t];
    float cg = (cosf(d * 3.14159265358979323846f / 90.0f) - 1.0f) / 1.0966227112321508f;
    meanv[t] = contrast[0] * 20.0f * expf(cg);
  }
  if (t < NMAXI) conv[t] = 0u;
  if (t < 2)     bar[t]  = 0u;
  if (blockIdx.x == 0 && threadIdx.x < 64) {
    int m = threadIdx.x;
    double x = cos(3.141592653589793 * (m + 0.75) / 64.5);
    double p0, p1, dp = 1.0;
    for (int it = 0; it < 60; ++it) {
      p0 = 1.0; p1 = x;
      for (int k = 2; k <= 64; ++k) {
        double p2 = ((2.0 * k - 1.0) * x * p1 - (k - 1.0) * p0) / (double)k;
        p0 = p1; p1 = p2;
      }
      dp = 64.0 * (x * p1 - p0) / (x * x - 1.0);
      double step = p1 / dp;
      x -= step;
      if (fabs(step) < 1e-15) break;
    }
    p0 = 1.0; p1 = x;
    for (int k = 2; k <= 64; ++k) {
      double p2 = ((2.0 * k - 1.0) * x * p1 - (k - 1.0) * p0) / (double)k;
      p0 = p1; p1 = p2;
    }
    dp = 64.0 * (x * p1 - p0) / (x * x - 1.0);
    double wgt = 2.0 / ((1.0 - x * x) * dp * dp);
    qn[63 - m] = (float)x;
    qw[63 - m] = (float)wgt;
  }
}

struct RowP {
  float eI, eE, pI, pE, dI, dE;
  const float* ur;
  int row;
};

__device__ __forceinline__ RowP make_rowp(int row,
    const float* __restrict__ hyper, const float* __restrict__ randu) {
  const float cdg = 0.017453292519943295f;
  const int ri = (row < NIB) ? 1 : 0;
  RowP rp;
  rp.eI = hyper[2 + ri]; rp.eE = hyper[0 + ri];
  rp.pI = hyper[6 + ri]; rp.pE = hyper[4 + ri];
  const float wI = cdg * hyper[10 + ri], wE = cdg * hyper[8 + ri];
  rp.dI = 4.0f * (wI * wI); rp.dE = 4.0f * (wE * wE);
  rp.ur = randu + (size_t)row * NN;
  rp.row = row;
  return rp;
}

template <int BASE, int K>
__device__ __forceinline__ void gen_chunk(const RowP& rp, int lane,
                                          const float* __restrict__ ctab) {
  const int j0 = K * 256 + (lane << 2);
  float w[4] = {0.0f, 0.0f, 0.0f, 0.0f};
  if (j0 + 3 < NN) {
    const float4 uv = *reinterpret_cast<const float4*>(rp.ur + j0);
    const float us[4] = {uv.x, uv.y, uv.z, uv.w};
#pragma unroll
    for (int q = 0; q < 4; ++q) {
      const int j = j0 + q;
      int idx = j - rp.row; idx += (idx < 0) ? NN : 0;
      const float ct   = ctab[idx];
      const float eff  = (j   < NIB) ? rp.eI : rp.eE;
      const float prob = (j   < NIB) ? rp.pI : rp.pE;
      const float den  = (idx < NIB) ? rp.dI : rp.dE;
      const float Z  = __expf(ct / den);
      const float tt = 32.0f * (prob * Z - us[q]);
      w[q] = eff / (1.0f + __expf(-tt));
    }
  }
  half2_t h01; h01.x = (_Float16)w[0]; h01.y = (_Float16)w[1];
  half2_t h23; h23.x = (_Float16)w[2]; h23.y = (_Float16)w[3];
  aw<BASE + 2 * K>(__builtin_bit_cast(unsigned, h01));
  aw<BASE + 2 * K + 1>(__builtin_bit_cast(unsigned, h23));
}

template <int BASE, int... Ks>
__device__ __forceinline__ void gen_row_seq(const RowP& rp, int lane,
    const float* __restrict__ ctab, std::integer_sequence<int, Ks...>) {
  (gen_chunk<BASE, Ks>(rp, lane, ctab), ...);
}

template <int K>
__device__ __forceinline__ void acc_chunk(const uint2* __restrict__ rh2,
    int lane, float& muA, float& varA, float& muB, float& varB,
    float& muC, float& varC) {
  const uint2 rr = rh2[K * 64 + lane];
  const unsigned a0 = ar<2 * K>(),       a1 = ar<2 * K + 1>();
  const unsigned b0 = ar<48 + 2 * K>(),  b1 = ar<48 + 2 * K + 1>();
  const unsigned c0 = ar<96 + 2 * K>(),  c1 = ar<96 + 2 * K + 1>();
  muA  = dot2acc(a0, rr.x, muA);        muA  = dot2acc(a1, rr.y, muA);
  varA = dot2acc(pksq(a0), rr.x, varA); varA = dot2acc(pksq(a1), rr.y, varA);
  muB  = dot2acc(b0, rr.x, muB);        muB  = dot2acc(b1, rr.y, muB);
  varB = dot2acc(pksq(b0), rr.x, varB); varB = dot2acc(pksq(b1), rr.y, varB);
  muC  = dot2acc(c0, rr.x, muC);        muC  = dot2acc(c1, rr.y, muC);
  varC = dot2acc(pksq(c0), rr.x, varC); varC = dot2acc(pksq(c1), rr.y, varC);
}

template <int... Ks>
__device__ __forceinline__ void acc_all(const uint2* __restrict__ rh2,
    int lane, float& muA, float& varA, float& muB, float& varB,
    float& muC, float& varC, std::integer_sequence<int, Ks...>) {
  (acc_chunk<Ks>(rh2, lane, muA, varA, muB, varB, muC, varC), ...);
}

// Persistent kernel. 250 blocks x 512 threads, 3 rows/wave. W lives in
// PHYSICAL AGPRs a0..a143 (fp16 pairs) via inline asm -- the register
// allocator cannot see or spill it (rounds 3-9: compiler-managed W was
// always spilled to scratch regardless of source form / geometry / hints).
__global__ __launch_bounds__(NTHR, 2) void solve_kernel(
    const float* __restrict__ hyper, const float* __restrict__ randu,
    const float* __restrict__ ctab, const float* __restrict__ meanv,
    const float* __restrict__ qn, const float* __restrict__ qw,
    float* __restrict__ g0, float* __restrict__ g1,
    float* __restrict__ blkmax, unsigned* __restrict__ bar,
    float* __restrict__ out)
{
  reserve_agprs();

  const int tid  = threadIdx.x;
  const int lane = tid & 63;
  const int wv   = tid >> 6;
  const int rowA = blockIdx.x * 24 + wv * 3;
  const int rowB = rowA + 1;
  const int rowC = rowA + 2;

  __shared__ uint2 rh2[NPAD / 4];     // fp16 r: rh2[i] = r[4i..4i+3]
  __shared__ float wmax[8];
  __shared__ float sflag[NAVGI];

  const float qnl = qn[lane];
  const float qwl = qw[lane];
  const float meanA = meanv[rowA];
  const float meanB = meanv[rowB];
  const float meanC = meanv[rowC];

  // ---- generate three rows' W into physical AGPRs ----
  {
    const RowP rpA = make_rowp(rowA, hyper, randu);
    gen_row_seq<0>(rpA, lane, ctab, std::make_integer_sequence<int, 24>{});
    const RowP rpB = make_rowp(rowB, hyper, randu);
    gen_row_seq<48>(rpB, lane, ctab, std::make_integer_sequence<int, 24>{});
    const RowP rpC = make_rowp(rowC, hyper, randu);
    gen_row_seq<96>(rpC, lane, ctab, std::make_integer_sequence<int, 24>{});
  }

  // ---- fixed-point iteration ----
#pragma unroll 1
  for (int t = 0; t < NMAXI; ++t) {
    const float* rcur = (t & 1) ? g1 : g0;
    float*       rnxt = (t & 1) ? g0 : g1;

    // stage r (fp32 global -> fp16 LDS), uint2 entries (8B stride)
    {
      const float4* rc4 = reinterpret_cast<const float4*>(rcur);
#pragma unroll
      for (int s = 0; s < 3; ++s) {
        const int i = tid + s * NTHR;
        const float4 v = rc4[i];
        half2_t a, b;
        a.x = (_Float16)v.x; a.y = (_Float16)v.y;
        b.x = (_Float16)v.z; b.y = (_Float16)v.w;
        uint2 p;
        p.x = __builtin_bit_cast(unsigned, a);
        p.y = __builtin_bit_cast(unsigned, b);
        rh2[i] = p;
      }
    }
    __syncthreads();

    // fused W.r and (W*W).r for three rows from AGPRs
    float muA = 0.0f, varA = 0.0f, muB = 0.0f, varB = 0.0f;
    float muC = 0.0f, varC = 0.0f;
    acc_all(rh2, lane, muA, varA, muB, varB, muC, varC,
            std::make_integer_sequence<int, 24>{});
#pragma unroll
    for (int off = 32; off > 0; off >>= 1) {
      muA  += __shfl_xor(muA, off);
      varA += __shfl_xor(varA, off);
      muB  += __shfl_xor(muB, off);
      varB += __shfl_xor(varB, off);
      muC  += __shfl_xor(muC, off);
      varC += __shfl_xor(varC, off);
    }

    float ratioM = 0.0f;
#pragma unroll
    for (int rr = 0; rr < 3; ++rr) {
      const int   row = (rr == 0) ? rowA : (rr == 1) ? rowB : rowC;
      float mu  = ((rr == 0) ? muA  : (rr == 1) ? muB  : muC)
                + ((rr == 0) ? meanA : (rr == 1) ? meanB : meanC);
      float var = ((rr == 0) ? varA : (rr == 1) ? varB : varC) + 25.0f;
      const float sig = sqrtf(var);
      const float uu = (20.0f - mu) / sig;
      const float ll = (10.0f - mu) / sig;
      const float cc = 0.5f * (uu + ll);
      const float hh = 0.5f * (uu - ll);
      const float x = cc + hh * qnl;
      float term    = qwl * erfcx_inl(-x);
#pragma unroll
      for (int off = 32; off > 0; off >>= 1) term += __shfl_xor(term, off);
      const float integ = hh * term;
      const float phiv  = 1.0f / (1.0f + SQRT_PI_F * fmaxf(integ, 0.0f));

      const float rold = rcur[row];           // exact fp32 state
      const float dx   = (phiv - rold) * 0.1f;
      const float rnew = rold + dx;
      ratioM = fmaxf(ratioM, fabsf(dx) / fmaxf(1.0f, fabsf(rnew)));
      if (lane == 0) {
        if (t == NMAXI - 1) out[row] = rnew;
        else                rnxt[row] = rnew;
      }
    }
    if (lane == 0) wmax[wv] = ratioM;
    __syncthreads();
    if (tid == 0) {
      float m = wmax[0];
#pragma unroll
      for (int q = 1; q < 8; ++q) m = fmaxf(m, wmax[q]);
      blkmax[(size_t)t * NBLK + blockIdx.x] = m;
    }
    gbar(bar, bar + 1, tid);
  }

  // ---- convergence epilogue: block 0 reduces blkmax over [50,80) ----
  if (blockIdx.x == 0) {
#pragma unroll
    for (int s = 0; s < 4; ++s) {
      const int t = 50 + wv + 8 * s;
      if (t < NMAXI) {
        float m = 0.0f;
        for (int p = lane; p < NBLK; p += 64)
          m = fmaxf(m, blkmax[(size_t)t * NBLK + p]);
#pragma unroll
        for (int off = 32; off > 0; off >>= 1)
          m = fmaxf(m, __shfl_xor(m, off));
        if (lane == 0) sflag[t - 50] = (m < 1e-5f) ? 1.0f : 0.0f;
      }
    }
    __syncthreads();
    if (tid == 0) {
      float s = 0.0f;
#pragma unroll
      for (int q = 0; q < NAVGI; ++q) s += sflag[q];
      out[NN] = s / 30.0f;
    }
  }
}

// ---------------- fallback path (non-persistent, fp16 W in ws) -------------
__global__ __launch_bounds__(256) void genw_f16_kernel(
    const float* __restrict__ hyper, const float* __restrict__ randu,
    const float* __restrict__ ctab, unsigned short* __restrict__ Wp)
{
  const int row = blockIdx.x;
  const int lane = (int)threadIdx.x;
  const float cdg = 0.017453292519943295f;
  const int ri  = (row < NIB) ? 1 : 0;
  const float eI = hyper[2 + ri], eE = hyper[0 + ri];
  const float pI = hyper[6 + ri], pE = hyper[4 + ri];
  const float wI = cdg * hyper[10 + ri], wE = cdg * hyper[8 + ri];
  const float dI = 4.0f * (wI * wI), dE = 4.0f * (wE * wE);
  const float* ur = randu + (size_t)row * NN;
  unsigned short* wrow = Wp + (size_t)row * NPAD;
  for (int j0 = lane * 8; j0 < NPAD; j0 += 2048) {
    float w[8];
    if (j0 < NN) {
      const float4 u0 = *reinterpret_cast<const float4*>(ur + j0);
      const float4 u1 = *reinterpret_cast<const float4*>(ur + j0 + 4);
      const float us[8] = {u0.x, u0.y, u0.z, u0.w, u1.x, u1.y, u1.z, u1.w};
#pragma unroll
      for (int q = 0; q < 8; ++q) {
        const int j = j0 + q;
        int idx = j - row; idx += (idx < 0) ? NN : 0;
        const float ct   = ctab[idx];
        const float eff  = (j   < NIB) ? eI : eE;
        const float prob = (j   < NIB) ? pI : pE;
        const float den  = (idx < NIB) ? dI : dE;
        const float Z  = __expf(ct / den);
        const float tt = 32.0f * (prob * Z - us[q]);
        w[q] = eff / (1.0f + __expf(-tt));
      }
    } else {
#pragma unroll
      for (int q = 0; q < 8; ++q) w[q] = 0.0f;
    }
    uint4 pk; half2_t h;
    h.x = (_Float16)w[0]; h.y = (_Float16)w[1];
    pk.x = __builtin_bit_cast(unsigned, h);
    h.x = (_Float16)w[2]; h.y = (_Float16)w[3];
    pk.y = __builtin_bit_cast(unsigned, h);
    h.x = (_Float16)w[4]; h.y = (_Float16)w[5];
    pk.z = __builtin_bit_cast(unsigned, h);
    h.x = (_Float16)w[6]; h.y = (_Float16)w[7];
    pk.w = __builtin_bit_cast(unsigned, h);
    *reinterpret_cast<uint4*>(wrow + j0) = pk;
  }
}

__global__ __launch_bounds__(256) void iter_f16_kernel(
    const unsigned short* __restrict__ Wp, const float* __restrict__ rin,
    float* __restrict__ rout, const float* __restrict__ meanv,
    const float* __restrict__ qn, const float* __restrict__ qw,
    unsigned* __restrict__ convslot)
{
  const int row  = blockIdx.x;
  const int tid  = threadIdx.x;
  const int lane = tid & 63;
  const int wvid = tid >> 6;
  __shared__ float smu[4], svar[4];
  float mu = 0.0f, var = 0.0f;
  const unsigned short* wrow = Wp + (size_t)row * NPAD;
#pragma unroll
  for (int k = 0; k < 3; ++k) {
    const int j0 = k * 2048 + tid * 8;
    const uint4 a = *reinterpret_cast<const uint4*>(wrow + j0);
    const float4 r0 = *reinterpret_cast<const float4*>(rin + j0);
    const float4 r1 = *reinterpret_cast<const float4*>(rin + j0 + 4);
    const half2_t h0 = __builtin_bit_cast(half2_t, a.x);
    const half2_t h1 = __builtin_bit_cast(half2_t, a.y);
    const half2_t h2 = __builtin_bit_cast(half2_t, a.z);
    const half2_t h3 = __builtin_bit_cast(half2_t, a.w);
    const float w0 = (float)h0.x, w1 = (float)h0.y;
    const float w2 = (float)h1.x, w3 = (float)h1.y;
    const float w4 = (float)h2.x, w5 = (float)h2.y;
    const float w6 = (float)h3.x, w7 = (float)h3.y;
    mu  += w0 * r0.x + w1 * r0.y + w2 * r0.z + w3 * r0.w
         + w4 * r1.x + w5 * r1.y + w6 * r1.z + w7 * r1.w;
    var += w0 * w0 * r0.x + w1 * w1 * r0.y + w2 * w2 * r0.z + w3 * w3 * r0.w
         + w4 * w4 * r1.x + w5 * w5 * r1.y + w6 * w6 * r1.z + w7 * w7 * r1.w;
  }
#pragma unroll
  for (int off = 32; off > 0; off >>= 1) {
    mu  += __shfl_xor(mu, off);
    var += __shfl_xor(var, off);
  }
  if (lane == 0) { smu[wvid] = mu; svar[wvid] = var; }
  __syncthreads();
  if (tid < 64) {
    mu  = smu[0] + smu[1] + smu[2] + smu[3];
    var = svar[0] + svar[1] + svar[2] + svar[3];
    mu += meanv[row]; var += 25.0f;
    const float sig = sqrtf(var);
    const float uu = (20.0f - mu) / sig;
    const float ll = (10.0f - mu) / sig;
    const float cc = 0.5f * (uu + ll);
    const float hh = 0.5f * (uu - ll);
    const float x = cc + hh * qn[lane];
    float term    = qw[lane] * erfcx_inl(-x);
#pragma unroll
    for (int off = 32; off > 0; off >>= 1) term += __shfl_xor(term, off);
    const float integ = hh * term;
    const float phiv  = 1.0f / (1.0f + SQRT_PI_F * fmaxf(integ, 0.0f));
    const float rold = rin[row];
    const float dx   = (phiv - rold) * 0.1f;
    const float rnew = rold + dx;
    if (lane == 0) {
      rout[row] = rnew;
      const float ratio = fabsf(dx) / fmaxf(1.0f, fabsf(rnew));
      atomicMax(convslot, __float_as_uint(ratio));
    }
  }
}

__global__ __launch_bounds__(256) void final_kernel(
    const float* __restrict__ rfin, const unsigned* __restrict__ conv,
    float* __restrict__ out)
{
  int t = blockIdx.x * 256 + threadIdx.x;
  if (t < NN) out[t] = rfin[t];
  if (t == 6000) {
    float s = 0.0f;
    for (int k = NMAXI - NAVGI; k < NMAXI; ++k)
      s += (__uint_as_float(conv[k]) < 1e-5f) ? 1.0f : 0.0f;
    out[NN] = s / 30.0f;
  }
}

extern "C" void kernel_launch(void* const* d_in, const int* in_sizes, int n_in,
                              void* d_out, int out_size, void* d_ws, size_t ws_size,
                              hipStream_t stream) {
  const float* hyper    = (const float*)d_in[0];
  const float* contrast = (const float*)d_in[1];
  const float* grat     = (const float*)d_in[2];
  const float* pref     = (const float*)d_in[3];
  const float* randu    = (const float*)d_in[4];
  float* out = (float*)d_out;

  char* ws = (char*)d_ws;
  float*    g0     = (float*)(ws + 0);       // 6144 f
  float*    g1     = (float*)(ws + 24576);   // 6144 f
  float*    mn     = (float*)(ws + 49152);   // 6000 f
  float*    ctab   = (float*)(ws + 73152);   // 6000 f
  float*    qn     = (float*)(ws + 97152);   // 64 f
  float*    qw     = (float*)(ws + 97408);   // 64 f
  unsigned* conv   = (unsigned*)(ws + 97664);// 80 u32 (fallback)
  unsigned* bar    = (unsigned*)(ws + 97984);// 2 u32
  float*    blkmax = (float*)(ws + 98304);   // 80*250 f
  unsigned short* Wp = (unsigned short*)(ws + 524288); // fp16 W (fallback)

  init_kernel<<<24, 256, 0, stream>>>(contrast, grat, pref, g0, g1, mn, ctab,
                                      qn, qw, conv, bar);

  // Cooperative capacity pre-check (deadlock guard).
  bool coop_ok = false;
  {
    int nb = 0;
    hipError_t e = hipOccupancyMaxActiveBlocksPerMultiprocessor(
        &nb, (const void*)solve_kernel, NTHR, 0);
    int cus = 0, dev = 0;
    if (hipGetDevice(&dev) != hipSuccess) dev = 0;
    if (hipDeviceGetAttribute(&cus, hipDeviceAttributeMultiprocessorCount,
                              dev) != hipSuccess || cus <= 0)
      cus = 256;
    coop_ok = (e == hipSuccess) && ((long)nb * cus >= NBLK);
  }

  if (coop_ok) {
    const float* a_hyper = hyper;  const float* a_randu = randu;
    const float* a_ctab  = ctab;   const float* a_mn    = mn;
    const float* a_qn    = qn;     const float* a_qw    = qw;
    float* a_g0 = g0; float* a_g1 = g1;
    float* a_bm = blkmax; unsigned* a_bar = bar; float* a_out = out;
    void* args[11] = {&a_hyper, &a_randu, &a_ctab, &a_mn, &a_qn, &a_qw,
                      &a_g0, &a_g1, &a_bm, &a_bar, &a_out};
    hipError_t err = hipLaunchCooperativeKernel(
        (const void*)solve_kernel, dim3(NBLK), dim3(NTHR), args, 0, stream);
    if (err == hipSuccess) return;
  }

  // fallback: non-persistent, fp16 W
  genw_f16_kernel<<<NN, 256, 0, stream>>>(hyper, randu, ctab, Wp);
  float* rb[2] = {g0, g1};
  for (int t = 0; t < NMAXI; ++t) {
    const float* rin = rb[t & 1];
    float*       rou = rb[(t + 1) & 1];
    iter_f16_kernel<<<NN, 256, 0, stream>>>(Wp, rin, rou, mn, qn, qw, conv + t);
  }
  final_kernel<<<24, 256, 0, stream>>>(rb[0], conv, out);
}